// Round 1
// baseline (23434.013 us; speedup 1.0000x reference)
//
#include <hip/hip_runtime.h>
#include <cmath>

namespace {
constexpr int T_STEPS = 2048;
constexpr int B_SZ = 256;
constexpr int I_SZ = 64;
constexpr int H_SZ = 256;
constexpr int G_SZ = 3 * H_SZ;   // 768 gate rows (r,z,n stacked)
constexpr int BC = 2;            // batch elements per block
constexpr int NB = B_SZ / BC;    // 128 blocks
constexpr int NTHR = G_SZ;       // 768 threads: one per gate row
}

// ---- weight transposes into workspace (coalesced streaming layout) ----
__global__ void transpose_whh(const float* __restrict__ W, float* __restrict__ WT) {
  int id = blockIdx.x * blockDim.x + threadIdx.x;  // G*H elements
  if (id >= G_SZ * H_SZ) return;
  int k = id % H_SZ;
  int g = id / H_SZ;
  WT[(size_t)k * G_SZ + g] = W[id];
}
__global__ void transpose_wih(const float* __restrict__ W, float* __restrict__ WT) {
  int id = blockIdx.x * blockDim.x + threadIdx.x;  // G*I elements
  if (id >= G_SZ * I_SZ) return;
  int k = id % I_SZ;
  int g = id / I_SZ;
  WT[(size_t)k * G_SZ + g] = W[id];
}
__global__ void transpose_wout(const float* __restrict__ W, float* __restrict__ WT) {
  int id = blockIdx.x * blockDim.x + threadIdx.x;  // I*H elements
  if (id >= I_SZ * H_SZ) return;
  int k = id % H_SZ;
  int o = id / H_SZ;
  WT[(size_t)k * I_SZ + o] = W[id];
}

// ---- persistent GRU: each block owns BC batch elements for all T steps ----
__global__ __launch_bounds__(NTHR, 1) void gru_persist(
    const float* __restrict__ input,   // [T,B,I]
    const float* __restrict__ hidden,  // [1,B,3]
    const float* __restrict__ W_dec,   // [H,3]
    const float* __restrict__ b_dec,   // [H]
    const float* __restrict__ WT_ih,   // [I,G] transposed
    const float* __restrict__ WT_hh,   // [H,G] transposed
    const float* __restrict__ b_ih,    // [G]
    const float* __restrict__ b_hh,    // [G]
    const float* __restrict__ WT_out,  // [H,I] transposed
    const float* __restrict__ b_out,   // [I]
    float* __restrict__ out)           // [B,T,I]
{
  __shared__ float h_s[H_SZ][BC];
  __shared__ float x_s[I_SZ][BC];
  __shared__ float gi_s[G_SZ][BC];
  __shared__ float gh_s[G_SZ][BC];
  __shared__ float ps_s[BC][4][I_SZ];

  const int tid = threadIdx.x;
  const int b0 = blockIdx.x * BC;

  // h0 = hidden @ W_dec^T + b_dec
  if (tid < H_SZ) {
    const int j = tid;
    const float w0 = W_dec[j * 3 + 0];
    const float w1 = W_dec[j * 3 + 1];
    const float w2 = W_dec[j * 3 + 2];
    const float bd = b_dec[j];
    for (int c = 0; c < BC; ++c) {
      const float* hv = hidden + (size_t)(b0 + c) * 3;
      h_s[j][c] = fmaf(w0, hv[0], fmaf(w1, hv[1], fmaf(w2, hv[2], bd)));
    }
  }

  const int g = tid;                 // this thread's gate row
  const float bih = b_ih[g];
  const float bhh = b_hh[g];
  const float bo = b_out[tid % I_SZ];

  __syncthreads();

  for (int t = 0; t < T_STEPS; ++t) {
    // teacher forcing: x_t = (t==0) ? 0 : input[t-1]
    if (tid < BC * I_SZ) {
      const int c = tid / I_SZ;
      const int i = tid % I_SZ;
      float v = 0.0f;
      if (t > 0) v = input[((size_t)(t - 1) * B_SZ + (b0 + c)) * I_SZ + i];
      x_s[i][c] = v;
    }
    __syncthreads();

    // gi = W_ih @ x + b_ih ; gh = W_hh @ h + b_hh   (row g, BC batches)
    float a0 = bih, a1 = bih;
    #pragma unroll 8
    for (int k = 0; k < I_SZ; ++k) {
      const float w = WT_ih[(size_t)k * G_SZ + g];
      a0 = fmaf(w, x_s[k][0], a0);
      a1 = fmaf(w, x_s[k][1], a1);
    }
    float c0 = bhh, c1 = bhh;
    #pragma unroll 8
    for (int k = 0; k < H_SZ; ++k) {
      const float w = WT_hh[(size_t)k * G_SZ + g];
      c0 = fmaf(w, h_s[k][0], c0);
      c1 = fmaf(w, h_s[k][1], c1);
    }
    gi_s[g][0] = a0; gi_s[g][1] = a1;
    gh_s[g][0] = c0; gh_s[g][1] = c1;
    __syncthreads();

    // gate combine + state update (threads j < H)
    if (tid < H_SZ) {
      const int j = tid;
      #pragma unroll
      for (int c = 0; c < BC; ++c) {
        const float ir = gi_s[j][c]          + gh_s[j][c];
        const float iz = gi_s[j + H_SZ][c]   + gh_s[j + H_SZ][c];
        const float in = gi_s[j + 2*H_SZ][c];
        const float hn = gh_s[j + 2*H_SZ][c];
        const float r = 1.0f / (1.0f + __expf(-ir));
        const float z = 1.0f / (1.0f + __expf(-iz));
        const float n = tanhf(fmaf(r, hn, in));
        const float hp = h_s[j][c];
        h_s[j][c] = fmaf(z, hp - n, n);   // (1-z)*n + z*h
      }
    }
    __syncthreads();

    // out = W_out @ h_new + b_out, split dot over 4 quarters
    if (tid < I_SZ * BC * 4) {
      const int o = tid % I_SZ;
      const int c = (tid / I_SZ) % BC;
      const int q = tid / (I_SZ * BC);
      float acc = 0.0f;
      #pragma unroll 8
      for (int kk = 0; kk < 64; ++kk) {
        const int k = q * 64 + kk;
        acc = fmaf(WT_out[(size_t)k * I_SZ + o], h_s[k][c], acc);
      }
      ps_s[c][q][o] = acc;
    }
    __syncthreads();
    if (tid < I_SZ * BC) {
      const int o = tid % I_SZ;
      const int c = tid / I_SZ;
      const float v = ps_s[c][0][o] + ps_s[c][1][o] + ps_s[c][2][o]
                    + ps_s[c][3][o] + bo;
      out[((size_t)(b0 + c) * T_STEPS + t) * I_SZ + o] = v;
    }
  }
}

extern "C" void kernel_launch(void* const* d_in, const int* in_sizes, int n_in,
                              void* d_out, int out_size, void* d_ws, size_t ws_size,
                              hipStream_t stream) {
  const float* input  = (const float*)d_in[0];
  const float* hidden = (const float*)d_in[1];
  const float* W_dec  = (const float*)d_in[2];
  const float* b_dec  = (const float*)d_in[3];
  const float* W_ih   = (const float*)d_in[4];
  const float* W_hh   = (const float*)d_in[5];
  const float* b_ih   = (const float*)d_in[6];
  const float* b_hh   = (const float*)d_in[7];
  const float* W_out  = (const float*)d_in[8];
  const float* b_out  = (const float*)d_in[9];
  float* out = (float*)d_out;

  float* WT_hh  = (float*)d_ws;                       // H*G floats
  float* WT_ih  = WT_hh + (size_t)H_SZ * G_SZ;        // I*G floats
  float* WT_out = WT_ih + (size_t)I_SZ * G_SZ;        // H*I floats

  transpose_whh<<<(G_SZ * H_SZ + 255) / 256, 256, 0, stream>>>(W_hh, WT_hh);
  transpose_wih<<<(G_SZ * I_SZ + 255) / 256, 256, 0, stream>>>(W_ih, WT_ih);
  transpose_wout<<<(I_SZ * H_SZ + 255) / 256, 256, 0, stream>>>(W_out, WT_out);

  gru_persist<<<NB, NTHR, 0, stream>>>(input, hidden, W_dec, b_dec,
                                       WT_ih, WT_hh, b_ih, b_hh,
                                       WT_out, b_out, out);
}

// Round 3
// 10449.774 us; speedup vs baseline: 2.2425x; 2.2425x over previous
//
#include <hip/hip_runtime.h>
#include <cmath>

namespace {
constexpr int T_STEPS = 2048;
constexpr int B_SZ = 256;
constexpr int I_SZ = 64;
constexpr int H_SZ = 256;
constexpr int BC = 16;            // batches per block
constexpr int NB = B_SZ / BC;     // 16 blocks
constexpr int NW = 16;            // waves per block
constexpr int NTHR = NW * 64;     // 1024 threads

// packed fragment region sizes in ushorts
constexpr int WHH_US = NW * 8 * 3 * 64 * 8;   // 196608 us (393KB)
constexpr int WIH_US = NW * 2 * 3 * 64 * 8;   // 49152 us
constexpr int WOUT_US = NW * 2 * 64 * 8;      // 16384 us
}

typedef __attribute__((ext_vector_type(8))) short s16x8;
typedef __attribute__((ext_vector_type(4))) short s16x4;
typedef __attribute__((ext_vector_type(4))) float f32x4;

__device__ __forceinline__ unsigned short bfr(float x) {
  unsigned u = __builtin_bit_cast(unsigned, x);
  u += 0x7fffu + ((u >> 16) & 1u);
  return (unsigned short)(u >> 16);
}

// sigma: element j of a fragment, lane-group g=(l>>4):  k = (j>>2)*16 + 4*g + (j&3)
// Used identically for A-packing (setup kernels) and B-reads (LDS) -> layout-proof.
__device__ __forceinline__ int sigma_k(int g, int j) {
  return ((j >> 2) << 4) + (g << 2) + (j & 3);
}

// ---- setup: pack weights into MFMA A-fragment streaming order (bf16) ----
__global__ void pack_whh(const float* __restrict__ W, unsigned short* __restrict__ dst) {
  int id = blockIdx.x * blockDim.x + threadIdx.x;
  if (id >= WHH_US) return;
  int j = id & 7, l = (id >> 3) & 63, g = (id / 512) % 3, kt = (id / 1536) & 7, w = id / 12288;
  int m = g * 256 + w * 16 + (l & 15);
  int k = kt * 32 + sigma_k(l >> 4, j);
  dst[id] = bfr(W[m * 256 + k]);
}
__global__ void pack_wih(const float* __restrict__ W, unsigned short* __restrict__ dst) {
  int id = blockIdx.x * blockDim.x + threadIdx.x;
  if (id >= WIH_US) return;
  int j = id & 7, l = (id >> 3) & 63, g = (id / 512) % 3, kt = (id / 1536) & 1, w = id / 3072;
  int m = g * 256 + w * 16 + (l & 15);
  int k = kt * 32 + sigma_k(l >> 4, j);
  dst[id] = bfr(W[m * 64 + k]);
}
__global__ void pack_wout(const float* __restrict__ W, unsigned short* __restrict__ dst) {
  int id = blockIdx.x * blockDim.x + threadIdx.x;
  if (id >= WOUT_US) return;
  int j = id & 7, l = (id >> 3) & 63, kk = (id / 512) & 1, w = id / 1024;
  int mt = w & 3, q = w >> 2;
  int m = mt * 16 + (l & 15);
  int k = (2 * q + kk) * 32 + sigma_k(l >> 4, j);
  dst[id] = bfr(W[m * 256 + k]);
}

__device__ __forceinline__ f32x4 MF(s16x8 a, s16x8 b, f32x4 c) {
  return __builtin_amdgcn_mfma_f32_16x16x32_bf16(a, b, c, 0, 0, 0);
}

// ---- persistent GRU: 16 blocks x 1024 threads, MFMA, L2-hot packed weights ----
__global__ __launch_bounds__(NTHR) void gru_mfma(
    const float* __restrict__ input,   // [T,B,I]
    const float* __restrict__ hidden,  // [1,B,3]
    const float* __restrict__ W_dec,   // [H,3]
    const float* __restrict__ b_dec,   // [H]
    const float* __restrict__ b_ih,    // [3H]
    const float* __restrict__ b_hh,    // [3H]
    const float* __restrict__ b_out,   // [I]
    const unsigned short* __restrict__ wsp,  // packed frags
    float* __restrict__ out)           // [B,T,I]
{
  __shared__ unsigned short h_buf[2][16 * 256];  // [c][k] bf16, XOR-swizzled
  __shared__ unsigned short x_buf[2][16 * 64];   // [c][i] bf16, XOR-swizzled
  __shared__ float po[4 * 16 * 64];              // out partials [q][c][o^swz]
  __shared__ float bias_s[1024];                 // brz[512], bni[256], bnh[256]

  const int tid = threadIdx.x;
  const int w = tid >> 6;
  const int l = tid & 63;
  const int c = l & 15;          // batch col for MFMA frags
  const int grp = l >> 4;        // lane group 0..3
  const int b0 = blockIdx.x * BC;

  const s16x8* whh_p = (const s16x8*)(wsp);
  const s16x8* wih_p = (const s16x8*)(wsp + WHH_US);
  const s16x8* wout_p = (const s16x8*)(wsp + WHH_US + WIH_US);

  // ---- prologue ----
  if (tid < 512) bias_s[tid] = b_ih[tid] + b_hh[tid];          // r,z merged
  else if (tid < 768) bias_s[tid] = b_ih[tid];                 // b_ih_n
  else bias_s[tid] = b_hh[tid - 256];                          // b_hh_n
  x_buf[0][tid] = 0;

  const float bout = b_out[tid & 63];

  // h0 = W_dec @ hidden + b_dec, rows j = w*16 + grp*4 + i, col c
  float hprev[4];
  {
    const float hv0 = hidden[(b0 + c) * 3 + 0];
    const float hv1 = hidden[(b0 + c) * 3 + 1];
    const float hv2 = hidden[(b0 + c) * 3 + 2];
    const int j0 = w * 16 + grp * 4;
    const int sw = c << 2;
    unsigned short hp[4];
#pragma unroll
    for (int i = 0; i < 4; ++i) {
      const int j = j0 + i;
      hprev[i] = fmaf(W_dec[j * 3 + 0], hv0,
                  fmaf(W_dec[j * 3 + 1], hv1,
                   fmaf(W_dec[j * 3 + 2], hv2, b_dec[j])));
      hp[i] = bfr(hprev[i]);
    }
    *(s16x4*)&h_buf[0][c * 256 + (j0 ^ sw)] = *(s16x4*)hp;
  }
  __syncthreads();

  const int j0v = w * 16 + grp * 4;
  const f32x4 brz_r = *(const f32x4*)&bias_s[j0v];
  const f32x4 brz_z = *(const f32x4*)&bias_s[256 + j0v];
  const f32x4 bni4 = *(const f32x4*)&bias_s[512 + j0v];
  const f32x4 bnh4 = *(const f32x4*)&bias_s[768 + j0v];
  const int sw = c << 2;   // XOR swizzle (ushort-index units)

  for (int t = 0; t < T_STEPS; ++t) {
    const int p = t & 1;
    const unsigned short* hb = h_buf[p];
    const unsigned short* xb = x_buf[p];
    unsigned short* hbn = h_buf[p ^ 1];
    unsigned short* xbn = x_buf[p ^ 1];

    // ---- phase A: gate MFMAs ----
    f32x4 ar{0.f, 0.f, 0.f, 0.f}, az{0.f, 0.f, 0.f, 0.f};
    f32x4 ani{0.f, 0.f, 0.f, 0.f}, anh{0.f, 0.f, 0.f, 0.f};

#pragma unroll
    for (int kt = 0; kt < 2; ++kt) {
      const int k0 = kt * 32 + (grp << 2);
      s16x4 lo = *(const s16x4*)&xb[c * 64 + (k0 ^ sw)];
      s16x4 hi = *(const s16x4*)&xb[c * 64 + ((k0 + 16) ^ sw)];
      s16x8 xf = __builtin_shufflevector(lo, hi, 0, 1, 2, 3, 4, 5, 6, 7);
      const int fb = ((w * 2 + kt) * 3) * 64 + l;
      ar = MF(wih_p[fb], xf, ar);
      az = MF(wih_p[fb + 64], xf, az);
      ani = MF(wih_p[fb + 128], xf, ani);
    }
#pragma unroll 2
    for (int kt = 0; kt < 8; ++kt) {
      const int k0 = kt * 32 + (grp << 2);
      s16x4 lo = *(const s16x4*)&hb[c * 256 + (k0 ^ sw)];
      s16x4 hi = *(const s16x4*)&hb[c * 256 + ((k0 + 16) ^ sw)];
      s16x8 hf = __builtin_shufflevector(lo, hi, 0, 1, 2, 3, 4, 5, 6, 7);
      const int fb = ((w * 8 + kt) * 3) * 64 + l;
      ar = MF(whh_p[fb], hf, ar);
      az = MF(whh_p[fb + 64], hf, az);
      anh = MF(whh_p[fb + 128], hf, anh);
    }

    // ---- phase B: gate combine (per-lane, rows j0v..j0v+3, col c) ----
    unsigned short hp[4];
#pragma unroll
    for (int i = 0; i < 4; ++i) {
      const float r = 1.f / (1.f + __expf(-(ar[i] + brz_r[i])));
      const float z = 1.f / (1.f + __expf(-(az[i] + brz_z[i])));
      const float nn = tanhf(ani[i] + bni4[i] + r * (anh[i] + bnh4[i]));
      const float h = fmaf(z, hprev[i] - nn, nn);
      hprev[i] = h;
      hp[i] = bfr(h);
    }
    // ---- phase C: write h_new, stage x_{t+1} = input[t] ----
    *(s16x4*)&hbn[c * 256 + (j0v ^ sw)] = *(s16x4*)hp;
    {
      const int xc = tid >> 6, xi = tid & 63;
      const float xv = input[((size_t)t * B_SZ + b0 + xc) * I_SZ + xi];
      xbn[xc * 64 + (xi ^ (xc << 2))] = bfr(xv);
    }
    __syncthreads();

    // ---- phase D: output projection partials on h_new ----
    {
      const int mt = w & 3, q = w >> 2;
      f32x4 ao{0.f, 0.f, 0.f, 0.f};
#pragma unroll
      for (int kk = 0; kk < 2; ++kk) {
        const int kt = q * 2 + kk;
        const int k0 = kt * 32 + (grp << 2);
        s16x4 lo = *(const s16x4*)&hbn[c * 256 + (k0 ^ sw)];
        s16x4 hi = *(const s16x4*)&hbn[c * 256 + ((k0 + 16) ^ sw)];
        s16x8 hf = __builtin_shufflevector(lo, hi, 0, 1, 2, 3, 4, 5, 6, 7);
        ao = MF(wout_p[(w * 2 + kk) * 64 + l], hf, ao);
      }
      const int o0 = mt * 16 + grp * 4;
      *(f32x4*)&po[q * 1024 + c * 64 + (o0 ^ ((c & 7) << 2))] = ao;
    }
    __syncthreads();

    // ---- phase E: reduce partials + store ----
    {
      const int oc = tid >> 6, oo = tid & 63;
      float v = bout;
#pragma unroll
      for (int q2 = 0; q2 < 4; ++q2)
        v += po[q2 * 1024 + oc * 64 + (oo ^ ((oc & 7) << 2))];
      out[((size_t)(b0 + oc) * T_STEPS + t) * I_SZ + oo] = v;
    }
  }
}

extern "C" void kernel_launch(void* const* d_in, const int* in_sizes, int n_in,
                              void* d_out, int out_size, void* d_ws, size_t ws_size,
                              hipStream_t stream) {
  const float* input  = (const float*)d_in[0];
  const float* hidden = (const float*)d_in[1];
  const float* W_dec  = (const float*)d_in[2];
  const float* b_dec  = (const float*)d_in[3];
  const float* W_ih   = (const float*)d_in[4];
  const float* W_hh   = (const float*)d_in[5];
  const float* b_ih   = (const float*)d_in[6];
  const float* b_hh   = (const float*)d_in[7];
  const float* W_out  = (const float*)d_in[8];
  const float* b_out  = (const float*)d_in[9];
  float* out = (float*)d_out;

  unsigned short* wsp = (unsigned short*)d_ws;

  pack_whh<<<(WHH_US + 255) / 256, 256, 0, stream>>>(W_hh, wsp);
  pack_wih<<<(WIH_US + 255) / 256, 256, 0, stream>>>(W_ih, wsp + WHH_US);
  pack_wout<<<(WOUT_US + 255) / 256, 256, 0, stream>>>(W_out, wsp + WHH_US + WIH_US);

  gru_mfma<<<NB, NTHR, 0, stream>>>(input, hidden, W_dec, b_dec,
                                    b_ih, b_hh, b_out, wsp, out);
}

// Round 4
// 9189.232 us; speedup vs baseline: 2.5502x; 1.1372x over previous
//
#include <hip/hip_runtime.h>
#include <cmath>

namespace {
constexpr int T_STEPS = 2048;
constexpr int B_SZ = 256;
constexpr int I_SZ = 64;
constexpr int H_SZ = 256;
constexpr int BC = 16;            // batches per block
constexpr int NB = B_SZ / BC;     // 16 blocks
constexpr int NW = 8;             // waves per block (2 per SIMD)
constexpr int NTHR = NW * 64;     // 512 threads

// packed fragment region sizes in ushorts
constexpr int WHH_US = 16 * 3 * 8 * 64 * 8;   // 196608 (393KB) ws*g*kt
constexpr int WIH_US = 16 * 3 * 2 * 64 * 8;   // 49152
constexpr int WOUT_US = 4 * 8 * 64 * 8;       // 16384
}

typedef __attribute__((ext_vector_type(8))) short s16x8;
typedef __attribute__((ext_vector_type(4))) short s16x4;
typedef __attribute__((ext_vector_type(4))) float f32x4;
typedef __attribute__((ext_vector_type(4))) unsigned int u32x4;

__device__ __forceinline__ unsigned short bfr(float x) {
  unsigned u = __builtin_bit_cast(unsigned, x);
  u += 0x7fffu + ((u >> 16) & 1u);
  return (unsigned short)(u >> 16);
}
__device__ __forceinline__ float bf2f(unsigned short us) {
  return __builtin_bit_cast(float, (unsigned)us << 16);
}

// sigma: element j, lane-group g: k = (j>>2)*16 + 4*g + (j&3).
// Used identically for A-packing and B-reads; any bijection cancels in MFMA.
__device__ __forceinline__ int sigma_k(int g, int j) {
  return ((j >> 2) << 4) + (g << 2) + (j & 3);
}

// ---- setup: pack weights into MFMA fragment streaming order (bf16) ----
__global__ void pack_whh(const float* __restrict__ W, unsigned short* __restrict__ dst) {
  int id = blockIdx.x * blockDim.x + threadIdx.x;
  if (id >= WHH_US) return;
  int j = id & 7, l = (id >> 3) & 63;
  int F = id >> 9;            // frag index
  int kt = F & 7, gg = F >> 3;
  int g = gg % 3, ws = gg / 3;                  // ws = w*2+s in [0,16)
  int m = g * 256 + ws * 16 + (l & 15);
  int k = kt * 32 + sigma_k(l >> 4, j);
  dst[id] = bfr(W[m * 256 + k]);
}
__global__ void pack_wih(const float* __restrict__ W, unsigned short* __restrict__ dst) {
  int id = blockIdx.x * blockDim.x + threadIdx.x;
  if (id >= WIH_US) return;
  int j = id & 7, l = (id >> 3) & 63;
  int f = id >> 9;            // f = (ws*3+g)*2 + kt
  int kt = f & 1, gg = f >> 1;
  int g = gg % 3, ws = gg / 3;
  int m = g * 256 + ws * 16 + (l & 15);
  int k = kt * 32 + sigma_k(l >> 4, j);
  dst[id] = bfr(W[m * 64 + k]);
}
__global__ void pack_wout(const float* __restrict__ W, unsigned short* __restrict__ dst) {
  int id = blockIdx.x * blockDim.x + threadIdx.x;
  if (id >= WOUT_US) return;
  int j = id & 7, l = (id >> 3) & 63;
  int f = id >> 9;            // f = mt*8 + kt
  int kt = f & 7, mt = f >> 3;
  int m = mt * 16 + (l & 15);
  int k = kt * 32 + sigma_k(l >> 4, j);
  dst[id] = bfr(W[m * 256 + k]);
}

__device__ __forceinline__ f32x4 MF(s16x8 a, s16x8 b, f32x4 c) {
  return __builtin_amdgcn_mfma_f32_16x16x32_bf16(a, b, c, 0, 0, 0);
}

// ---- persistent GRU: 16 blocks x 512 threads, W_hh register-resident ----
__global__ __launch_bounds__(NTHR, 2) void gru_mfma(
    const float* __restrict__ input,   // [T,B,I]
    const float* __restrict__ hidden,  // [1,B,3]
    const float* __restrict__ W_dec,   // [H,3]
    const float* __restrict__ b_dec,   // [H]
    const float* __restrict__ b_ih,    // [3H]
    const float* __restrict__ b_hh,    // [3H]
    const float* __restrict__ b_out,   // [I]
    const unsigned short* __restrict__ wsp,  // packed frags
    float* __restrict__ out)           // [B,T,I]
{
  __shared__ unsigned short wih_s[WIH_US];       // 96 KB
  __shared__ unsigned short h_buf[2][16 * 256];  // 16 KB, [c][k] bf16 XOR-swz
  __shared__ unsigned short x_buf[2][16 * 64];   // 4 KB
  __shared__ float bias_s[1024];                 // brz[512], bni[256], bnh[256]

  const int tid = threadIdx.x;
  const int w = tid >> 6;        // wave 0..7
  const int l = tid & 63;
  const int c = l & 15;          // batch col
  const int grp = l >> 4;        // lane group 0..3
  const int b0 = blockIdx.x * BC;
  const int sw = c << 2;         // LDS XOR swizzle (ushort-index units)

  const s16x8* whh_p = (const s16x8*)(wsp);
  const s16x8* wout_p = (const s16x8*)(wsp + WHH_US + WIH_US);

  // ---- load W_hh fragments into registers (static indices only) ----
  s16x8 whh[2][3][8];
#pragma unroll
  for (int s = 0; s < 2; ++s)
#pragma unroll
    for (int g = 0; g < 3; ++g)
#pragma unroll
      for (int kt = 0; kt < 8; ++kt)
        whh[s][g][kt] = whh_p[((((w * 2 + s) * 3 + g) * 8) + kt) * 64 + l];

  // ---- prologue: LDS fills ----
  {
    const u32x4* s4 = (const u32x4*)(wsp + WHH_US);
    u32x4* d4 = (u32x4*)wih_s;
#pragma unroll
    for (int i = 0; i < WIH_US / 8 / NTHR; ++i)
      d4[i * NTHR + tid] = s4[i * NTHR + tid];
  }
  bias_s[tid] = b_ih[tid] + b_hh[tid];                       // rows 0..511 (r,z)
  if (tid < 256) bias_s[512 + tid] = b_ih[512 + tid];        // bni
  else bias_s[512 + tid] = b_hh[256 + tid];                  // bnh
  *(unsigned*)&x_buf[0][tid * 2] = 0;

  f32x4 bo4 = {0.f, 0.f, 0.f, 0.f};
  if (w < 4) bo4 = *(const f32x4*)&b_out[w * 16 + grp * 4];

  // h0 = W_dec @ hidden + b_dec for this wave's rows
  {
    const float hv0 = hidden[(b0 + c) * 3 + 0];
    const float hv1 = hidden[(b0 + c) * 3 + 1];
    const float hv2 = hidden[(b0 + c) * 3 + 2];
#pragma unroll
    for (int s = 0; s < 2; ++s) {
      const int j0s = (w * 2 + s) * 16 + grp * 4;
      unsigned short hp[4];
#pragma unroll
      for (int i = 0; i < 4; ++i) {
        const int j = j0s + i;
        hp[i] = bfr(fmaf(W_dec[j * 3 + 0], hv0,
                     fmaf(W_dec[j * 3 + 1], hv1,
                      fmaf(W_dec[j * 3 + 2], hv2, b_dec[j]))));
      }
      *(s16x4*)&h_buf[0][c * 256 + (j0s ^ sw)] = *(s16x4*)hp;
    }
  }
  __syncthreads();

  for (int t = 0; t < T_STEPS; ++t) {
    const int p = t & 1;
    const unsigned short* hb = h_buf[p];
    const unsigned short* xb = x_buf[p];
    unsigned short* hbn = h_buf[p ^ 1];
    unsigned short* xbn = x_buf[p ^ 1];

    // acc init from bias (broadcast LDS reads)
    f32x4 ar[2], az[2], ani[2], anh[2];
#pragma unroll
    for (int s = 0; s < 2; ++s) {
      const int m = (w * 2 + s) * 16 + grp * 4;
      ar[s] = *(const f32x4*)&bias_s[m];
      az[s] = *(const f32x4*)&bias_s[256 + m];
      ani[s] = *(const f32x4*)&bias_s[512 + m];
      anh[s] = *(const f32x4*)&bias_s[768 + m];
    }

    // x-side MFMAs (W_ih from LDS)
#pragma unroll
    for (int kt = 0; kt < 2; ++kt) {
      const int k0 = kt * 32 + (grp << 2);
      s16x4 lo = *(const s16x4*)&xb[c * 64 + (k0 ^ sw)];
      s16x4 hi = *(const s16x4*)&xb[c * 64 + ((k0 + 16) ^ sw)];
      s16x8 xf = __builtin_shufflevector(lo, hi, 0, 1, 2, 3, 4, 5, 6, 7);
#pragma unroll
      for (int s = 0; s < 2; ++s) {
        const int fb = (w * 2 + s) * 6 + kt;   // frag (ws*3+g)*2+kt, g=0
        ar[s]  = MF(*(const s16x8*)&wih_s[(fb    ) * 512 + l * 8], xf, ar[s]);
        az[s]  = MF(*(const s16x8*)&wih_s[(fb + 2) * 512 + l * 8], xf, az[s]);
        ani[s] = MF(*(const s16x8*)&wih_s[(fb + 4) * 512 + l * 8], xf, ani[s]);
      }
    }

    // h-side MFMAs (W_hh from registers; one hf live at a time)
#pragma unroll
    for (int kt = 0; kt < 8; ++kt) {
      const int k0 = kt * 32 + (grp << 2);
      s16x4 lo = *(const s16x4*)&hb[c * 256 + (k0 ^ sw)];
      s16x4 hi = *(const s16x4*)&hb[c * 256 + ((k0 + 16) ^ sw)];
      s16x8 hf = __builtin_shufflevector(lo, hi, 0, 1, 2, 3, 4, 5, 6, 7);
#pragma unroll
      for (int s = 0; s < 2; ++s) {
        ar[s]  = MF(whh[s][0][kt], hf, ar[s]);
        az[s]  = MF(whh[s][1][kt], hf, az[s]);
        anh[s] = MF(whh[s][2][kt], hf, anh[s]);
      }
    }

    // gate combine + h_new write (hprev re-read from LDS as bf16)
#pragma unroll
    for (int s = 0; s < 2; ++s) {
      const int j0s = (w * 2 + s) * 16 + grp * 4;
      s16x4 hp4 = *(const s16x4*)&hb[c * 256 + (j0s ^ sw)];
      unsigned short hpn[4];
#pragma unroll
      for (int i = 0; i < 4; ++i) {
        const float r = 1.f / (1.f + __expf(-ar[s][i]));
        const float z = 1.f / (1.f + __expf(-az[s][i]));
        const float nn = tanhf(fmaf(r, anh[s][i], ani[s][i]));
        const float h = fmaf(z, bf2f((unsigned short)hp4[i]) - nn, nn);
        hpn[i] = bfr(h);
      }
      *(s16x4*)&hbn[c * 256 + (j0s ^ sw)] = *(s16x4*)hpn;
    }

    // stage x_{t+1} = input[t]
    {
      const int xc = tid >> 5;
      const int xi = (tid & 31) * 2;
      const float* xs = &input[((size_t)t * B_SZ + b0 + xc) * I_SZ + xi];
      const unsigned pk = (unsigned)bfr(xs[0]) | ((unsigned)bfr(xs[1]) << 16);
      *(unsigned*)&xbn[xc * 64 + (xi ^ (xc << 2))] = pk;
    }
    __syncthreads();

    // out-projection on h_new: waves 0..3, full K, W_out streamed from L2
    if (w < 4) {
      f32x4 ao = bo4;
#pragma unroll
      for (int kt = 0; kt < 8; ++kt) {
        const int k0 = kt * 32 + (grp << 2);
        s16x4 lo = *(const s16x4*)&hbn[c * 256 + (k0 ^ sw)];
        s16x4 hi = *(const s16x4*)&hbn[c * 256 + ((k0 + 16) ^ sw)];
        s16x8 hf = __builtin_shufflevector(lo, hi, 0, 1, 2, 3, 4, 5, 6, 7);
        ao = MF(wout_p[(w * 8 + kt) * 64 + l], hf, ao);
      }
      *(f32x4*)&out[((size_t)(b0 + c) * T_STEPS + t) * I_SZ + w * 16 + grp * 4] = ao;
    }
  }
}

extern "C" void kernel_launch(void* const* d_in, const int* in_sizes, int n_in,
                              void* d_out, int out_size, void* d_ws, size_t ws_size,
                              hipStream_t stream) {
  const float* input  = (const float*)d_in[0];
  const float* hidden = (const float*)d_in[1];
  const float* W_dec  = (const float*)d_in[2];
  const float* b_dec  = (const float*)d_in[3];
  const float* W_ih   = (const float*)d_in[4];
  const float* W_hh   = (const float*)d_in[5];
  const float* b_ih   = (const float*)d_in[6];
  const float* b_hh   = (const float*)d_in[7];
  const float* W_out  = (const float*)d_in[8];
  const float* b_out  = (const float*)d_in[9];
  float* out = (float*)d_out;

  unsigned short* wsp = (unsigned short*)d_ws;

  pack_whh<<<(WHH_US + 255) / 256, 256, 0, stream>>>(W_hh, wsp);
  pack_wih<<<(WIH_US + 255) / 256, 256, 0, stream>>>(W_ih, wsp + WHH_US);
  pack_wout<<<(WOUT_US + 255) / 256, 256, 0, stream>>>(W_out, wsp + WHH_US + WIH_US);

  gru_mfma<<<NB, NTHR, 0, stream>>>(input, hidden, W_dec, b_dec,
                                    b_ih, b_hh, b_out, wsp, out);
}